// Round 1
// baseline (386.025 us; speedup 1.0000x reference)
//
#include <hip/hip_runtime.h>
#include <math.h>

#define NN   128
#define CDIM 256
#define BV   8
#define SS   32
#define MM   64
#define RR   128          // M*K pos rows
#define PP   8256         // N*(N+1)/2
#define NCOL 66048        // B*PP
#define NBLK 1032         // NCOL/64
#define TEMP 0.1f
#define NEGIOU 0.5f

// ---------------- Kernel 1: exact top-2 per moment (tie-break: lower flat idx) ----
__global__ __launch_bounds__(256) void topk_kernel(const float* __restrict__ iou2ds,
                                                   int* __restrict__ topk) {
    int m = blockIdx.x;
    int tid = threadIdx.x;
    const float* src = iou2ds + (size_t)m * NN * NN;
    float v1 = -1e30f, v2 = -1e30f;
    int k1 = 0x7fffffff, k2 = 0x7fffffff;
    for (int k = tid; k < NN * NN; k += 256) {
        int i = k >> 7, j = k & 127;
        if (j < i) continue;                       // upper-triangular mask
        float v = src[k];
        if (v > v1 || (v == v1 && k < k1)) { v2 = v1; k2 = k1; v1 = v; k1 = k; }
        else if (v > v2 || (v == v2 && k < k2)) { v2 = v; k2 = k; }
    }
    __shared__ float sv[512];
    __shared__ int   sk[512];
    sv[tid * 2] = v1; sv[tid * 2 + 1] = v2;
    sk[tid * 2] = k1; sk[tid * 2 + 1] = k2;
    __syncthreads();
    if (tid == 0) {
        float b1 = -1e30f, b2 = -1e30f; int c1 = 0x7fffffff, c2 = 0x7fffffff;
        for (int t = 0; t < 512; ++t) {
            float v = sv[t]; int k = sk[t];
            if (v > b1 || (v == b1 && k < c1)) { b2 = b1; c2 = c1; b1 = v; c1 = k; }
            else if (v > b2 || (v == b2 && k < c2)) { b2 = v; c2 = k; }
        }
        topk[m * 2] = c1; topk[m * 2 + 1] = c2;
    }
}

// ---------------- Kernel 2: pos_feats (normalized), row-major + transposed -------
__global__ __launch_bounds__(64) void posfeat_kernel(const float* __restrict__ vfeat,
                                                     const int* __restrict__ topk,
                                                     float* __restrict__ pos,
                                                     float* __restrict__ posT) {
    int r = blockIdx.x;            // 0..127  (= m*2 + k)
    int lane = threadIdx.x;        // 0..63
    int m = r >> 1;
    int b = m >> 3;
    int ij = topk[r];
    const float* base = vfeat + (size_t)b * CDIM * NN * NN + ij;
    float v[4];
    float ss = 0.0f;
#pragma unroll
    for (int q = 0; q < 4; ++q) {
        int c = lane + 64 * q;
        v[q] = base[(size_t)c * (NN * NN)];
        ss += v[q] * v[q];
    }
#pragma unroll
    for (int o = 32; o > 0; o >>= 1) ss += __shfl_xor(ss, o, 64);
    float inv = 1.0f / fmaxf(sqrtf(ss), 1e-12f);
#pragma unroll
    for (int q = 0; q < 4; ++q) {
        int c = lane + 64 * q;
        float val = v[q] * inv;
        pos[r * CDIM + c] = val;
        posT[c * RR + r]  = val;
    }
}

// ---------------- Kernel 3: fused GEMM + norm + exp + masked per-row sum ---------
// 64 columns per block, 128 rows, K=256. Thread tile: 4 cols x 8 rows.
#define COLS 64
#define TC   32
__global__ __launch_bounds__(256) void neg_kernel(const float* __restrict__ vfeat,
                                                  const float* __restrict__ iou2d,
                                                  const float* __restrict__ posT,
                                                  float* __restrict__ part) {
    __shared__ float sV[TC][COLS];     // 8 KB
    __shared__ float sP[TC][RR];       // 16 KB
    __shared__ int   sIJ[COLS];
    __shared__ int   sMask[COLS];
    __shared__ float sNorm[COLS];
    __shared__ float sNeg[RR];

    int tid = threadIdx.x;
    int gcol0 = blockIdx.x * COLS;
    int b = gcol0 / PP;                // blocks never straddle videos (8256 % 64 == 0)
    int p0 = gcol0 - b * PP;

    if (tid < RR) sNeg[tid] = 0.0f;
    if (tid < COLS) {
        int p = p0 + tid;
        // decode upper-tri p -> (i,j): offset(i) = i*(257-i)/2
        int i = (int)((257.0f - sqrtf(66049.0f - 8.0f * (float)p)) * 0.5f);
        if (i < 0) i = 0;
        while ((i + 1) * (257 - (i + 1)) / 2 <= p) ++i;
        while (i * (257 - i) / 2 > p) --i;
        int j = p - i * (257 - i) / 2 + i;
        int ij = i * NN + j;
        sIJ[tid] = ij;
        int mask = 0;
#pragma unroll
        for (int t = 0; t < 4; ++t) {
            float iv = iou2d[((size_t)(4 * b + t)) * (NN * NN) + ij];
            mask |= (iv > NEGIOU) ? (1 << t) : 0;
        }
        sMask[tid] = mask;
    }
    __syncthreads();

    int colgrp = tid & 15;     // 16 groups x 4 cols
    int rgrp   = tid >> 4;     // 16 groups x 8 rows
    int mycol  = tid & 63;     // staging column
    int wv     = tid >> 6;     // wave id
    int myij   = sIJ[mycol];
    const float* vbase = vfeat + (size_t)b * CDIM * NN * NN + myij;

    float acc[4][8];
#pragma unroll
    for (int q = 0; q < 4; ++q)
#pragma unroll
        for (int u = 0; u < 8; ++u) acc[q][u] = 0.0f;
    float nrm[4] = {0.f, 0.f, 0.f, 0.f};

    for (int ct = 0; ct < CDIM / TC; ++ct) {
        int c0 = ct * TC;
        // stage pos tile: 4096 consecutive floats (posT is c-major)
        const float4* gp = (const float4*)(posT + c0 * RR);
#pragma unroll
        for (int q = 0; q < 4; ++q)
            ((float4*)sP)[tid + 256 * q] = gp[tid + 256 * q];
        // stage video columns: each wave one cc-stripe of 64 cols
#pragma unroll
        for (int q = 0; q < 8; ++q) {
            int cc = q * 4 + wv;
            sV[cc][mycol] = vbase[(size_t)(c0 + cc) * (NN * NN)];
        }
        __syncthreads();
#pragma unroll
        for (int cc = 0; cc < TC; ++cc) {
            float4 v4 = *(const float4*)&sV[cc][colgrp * 4];
            float4 pa = *(const float4*)&sP[cc][rgrp * 8];
            float4 pb = *(const float4*)&sP[cc][rgrp * 8 + 4];
            float vv[4] = {v4.x, v4.y, v4.z, v4.w};
            float pv[8] = {pa.x, pa.y, pa.z, pa.w, pb.x, pb.y, pb.z, pb.w};
#pragma unroll
            for (int q = 0; q < 4; ++q)
#pragma unroll
                for (int u = 0; u < 8; ++u)
                    acc[q][u] = fmaf(vv[q], pv[u], acc[q][u]);
            if (rgrp == 0) {
#pragma unroll
                for (int q = 0; q < 4; ++q) nrm[q] = fmaf(vv[q], vv[q], nrm[q]);
            }
        }
        __syncthreads();
    }
    if (rgrp == 0) {
#pragma unroll
        for (int q = 0; q < 4; ++q) sNorm[colgrp * 4 + q] = nrm[q];
    }
    __syncthreads();

    // epilogue: cos = dot/||v||, e = exp(cos/T), masked accumulate per row
    float racc[8] = {0.f,0.f,0.f,0.f,0.f,0.f,0.f,0.f};
    bool ownvid = ((rgrp >> 1) == b);          // r>>4 == b, uniform per thread
    int sl0 = (rgrp * 2) & 3;                  // s_local for u<4
    int sl1 = (rgrp * 2 + 1) & 3;              // s_local for u>=4
#pragma unroll
    for (int q = 0; q < 4; ++q) {
        int jj = colgrp * 4 + q;
        float inv = 1.0f / (TEMP * fmaxf(sqrtf(sNorm[jj]), 1e-12f));
        int mask = sMask[jj];
        bool exc0 = ownvid && ((mask >> sl0) & 1);
        bool exc1 = ownvid && ((mask >> sl1) & 1);
#pragma unroll
        for (int u = 0; u < 8; ++u) {
            float e = __expf(acc[q][u] * inv);
            bool exc = (u < 4) ? exc0 : exc1;
            racc[u] += exc ? 0.0f : e;
        }
    }
#pragma unroll
    for (int u = 0; u < 8; ++u) atomicAdd(&sNeg[rgrp * 8 + u], racc[u]);
    __syncthreads();
    if (tid < RR) part[(size_t)tid * NBLK + blockIdx.x] = sNeg[tid];
}

// ---------------- Kernel 3.5: reduce per-block partials -> neg_sum[128] ----------
__global__ __launch_bounds__(256) void reduce_kernel(const float* __restrict__ part,
                                                     float* __restrict__ neg) {
    int r = blockIdx.x, tid = threadIdx.x;
    const float* row = part + (size_t)r * NBLK;
    float s = 0.0f;
    for (int t = tid; t < NBLK; t += 256) s += row[t];
#pragma unroll
    for (int o = 32; o > 0; o >>= 1) s += __shfl_xor(s, o, 64);
    __shared__ float sw[4];
    if ((tid & 63) == 0) sw[tid >> 6] = s;
    __syncthreads();
    if (tid == 0) neg[r] = sw[0] + sw[1] + sw[2] + sw[3];
}

// ---------------- Kernel 4: 512 pair dots + log-sum-exp + mean -------------------
__global__ __launch_bounds__(256) void loss_kernel(const float* __restrict__ pos,
                                                   const float* __restrict__ neg,
                                                   float* __restrict__ out) {
    int tid = threadIdx.x;
    float local = 0.0f;
    for (int e = tid; e < 512; e += 256) {
        int s  = e >> 4;
        int aa = (e >> 2) & 3;
        int bb = e & 3;
        int rr = s * 4 + aa;
        int pp = s * 4 + bb;
        const float4* pr = (const float4*)(pos + rr * CDIM);
        const float4* pq = (const float4*)(pos + pp * CDIM);
        float dot = 0.0f;
        for (int c = 0; c < CDIM / 4; ++c) {
            float4 a = pr[c], bv = pq[c];
            dot += a.x * bv.x + a.y * bv.y + a.z * bv.z + a.w * bv.w;
        }
        float x = dot / TEMP;                  // MARGIN = 0
        local += logf(__expf(x) + neg[rr]) - x;
    }
#pragma unroll
    for (int o = 32; o > 0; o >>= 1) local += __shfl_xor(local, o, 64);
    __shared__ float sred[4];
    if ((tid & 63) == 0) sred[tid >> 6] = local;
    __syncthreads();
    if (tid == 0) out[0] = (sred[0] + sred[1] + sred[2] + sred[3]) / 512.0f;
}

extern "C" void kernel_launch(void* const* d_in, const int* in_sizes, int n_in,
                              void* d_out, int out_size, void* d_ws, size_t ws_size,
                              hipStream_t stream) {
    (void)in_sizes; (void)n_in; (void)out_size; (void)ws_size;
    const float* vfeat  = (const float*)d_in[0];
    const float* iou2d  = (const float*)d_in[4];
    const float* iou2ds = (const float*)d_in[5];

    float* ws   = (float*)d_ws;
    float* pos  = ws;                        // 128*256
    float* posT = ws + 32768;                // 256*128
    int*   topk = (int*)(ws + 65536);        // 128 ints
    float* part = ws + 65536 + 128;          // 128*1032
    float* neg  = part + RR * NBLK;          // 128

    topk_kernel  <<<MM, 256, 0, stream>>>(iou2ds, topk);
    posfeat_kernel<<<RR, 64, 0, stream>>>(vfeat, topk, pos, posT);
    neg_kernel   <<<NBLK, 256, 0, stream>>>(vfeat, iou2d, posT, part);
    reduce_kernel<<<RR, 256, 0, stream>>>(part, neg);
    loss_kernel  <<<1, 256, 0, stream>>>(pos, neg, (float*)d_out);
}

// Round 2
// 257.158 us; speedup vs baseline: 1.5011x; 1.5011x over previous
//
#include <hip/hip_runtime.h>
#include <math.h>

#define NN    128
#define NN2   16384        // N*N
#define CDIM  256
#define BV    8
#define MM    64
#define RR    128          // M*K pos rows
#define PP    8256         // N*(N+1)/2
#define NBLK  1032         // 66048 / 64 cols per block
#define BPB   129          // blocks per video (8256/64)
#define TEMP  0.1f
#define NEGIOU 0.5f

typedef __attribute__((ext_vector_type(8))) short bf16x8;
typedef __attribute__((ext_vector_type(4))) float f32x4;

static __device__ __forceinline__ unsigned short f2bf(float x) {
    union { float f; unsigned u; } c; c.f = x;
    unsigned r = c.u + 0x7FFFu + ((c.u >> 16) & 1u);   // RNE
    return (unsigned short)(r >> 16);
}

// ---------------- Kernel 1a: partial top-2 per (moment, quarter) -----------------
__global__ __launch_bounds__(256) void topk_part_kernel(const float* __restrict__ iou2ds,
                                                        float* __restrict__ pv,
                                                        int* __restrict__ pk) {
    int m = blockIdx.x, q = blockIdx.y, tid = threadIdx.x;
    const float* src = iou2ds + (size_t)m * NN2;
    float v1 = -1e30f, v2 = -1e30f;
    int k1 = 0x7fffffff, k2 = 0x7fffffff;
    int base = q * 4096;
#pragma unroll
    for (int i = 0; i < 16; ++i) {
        int k = base + tid + 256 * i;
        int r = k >> 7, c = k & 127;
        if (c < r) continue;                     // upper-triangular mask
        float v = src[k];
        if (v > v1 || (v == v1 && k < k1)) { v2 = v1; k2 = k1; v1 = v; k1 = k; }
        else if (v > v2 || (v == v2 && k < k2)) { v2 = v; k2 = k; }
    }
    __shared__ float sv[512];  __shared__ int sk[512];
    __shared__ float sv2[128]; __shared__ int sk2[128];
    sv[tid * 2] = v1; sv[tid * 2 + 1] = v2;
    sk[tid * 2] = k1; sk[tid * 2 + 1] = k2;
    __syncthreads();
    if (tid < 64) {
        float b1 = -1e30f, b2 = -1e30f; int c1 = 0x7fffffff, c2 = 0x7fffffff;
        for (int t = tid * 8; t < tid * 8 + 8; ++t) {
            float v = sv[t]; int k = sk[t];
            if (v > b1 || (v == b1 && k < c1)) { b2 = b1; c2 = c1; b1 = v; c1 = k; }
            else if (v > b2 || (v == b2 && k < c2)) { b2 = v; c2 = k; }
        }
        sv2[tid * 2] = b1; sv2[tid * 2 + 1] = b2;
        sk2[tid * 2] = c1; sk2[tid * 2 + 1] = c2;
    }
    __syncthreads();
    if (tid == 0) {
        float b1 = -1e30f, b2 = -1e30f; int c1 = 0x7fffffff, c2 = 0x7fffffff;
        for (int t = 0; t < 128; ++t) {
            float v = sv2[t]; int k = sk2[t];
            if (v > b1 || (v == b1 && k < c1)) { b2 = b1; c2 = c1; b1 = v; c1 = k; }
            else if (v > b2 || (v == b2 && k < c2)) { b2 = v; c2 = k; }
        }
        pv[(m * 4 + q) * 2] = b1; pv[(m * 4 + q) * 2 + 1] = b2;
        pk[(m * 4 + q) * 2] = c1; pk[(m * 4 + q) * 2 + 1] = c2;
    }
}

// ---------------- Kernel 2: merge partials, pos fp32 + pos bf16 frag layout ------
// posFrag layout: [s=k>>5][mt=r>>4][slot=(r&15)|(((k>>3)&3)<<4)][j=k&7]  (ushort)
__global__ __launch_bounds__(64) void posfeat_kernel(const float* __restrict__ vfeat,
                                                     const float* __restrict__ pv,
                                                     const int* __restrict__ pk,
                                                     float* __restrict__ pos,
                                                     unsigned short* __restrict__ posFrag) {
    int r = blockIdx.x, lane = threadIdx.x;
    int m = r >> 1, b = m >> 3, kk = r & 1;
    float b1 = -1e30f, b2 = -1e30f; int c1 = 0x7fffffff, c2 = 0x7fffffff;
    for (int t = 0; t < 8; ++t) {
        float v = pv[m * 8 + t]; int k = pk[m * 8 + t];
        if (v > b1 || (v == b1 && k < c1)) { b2 = b1; c2 = c1; b1 = v; c1 = k; }
        else if (v > b2 || (v == b2 && k < c2)) { b2 = v; c2 = k; }
    }
    int ij = kk ? c2 : c1;
    const float* base = vfeat + (size_t)b * CDIM * NN2 + ij;
    float v[4];
    float ss = 0.0f;
#pragma unroll
    for (int q = 0; q < 4; ++q) {
        int c = lane + 64 * q;
        v[q] = base[(size_t)c * NN2];
        ss += v[q] * v[q];
    }
#pragma unroll
    for (int o = 32; o > 0; o >>= 1) ss += __shfl_xor(ss, o, 64);
    float inv = 1.0f / fmaxf(sqrtf(ss), 1e-12f);
#pragma unroll
    for (int q = 0; q < 4; ++q) {
        int c = lane + 64 * q;
        float val = v[q] * inv;
        pos[r * CDIM + c] = val;
        int idx = (((c >> 5) * 8 + (r >> 4)) * 64 + ((r & 15) | (((c >> 3) & 3) << 4))) * 8 + (c & 7);
        posFrag[idx] = f2bf(val);
    }
}

// ---------------- Kernel 3: MFMA tall-skinny GEMM + norm + exp + masked row-sum --
// Block: 512 thr (8 waves), 128 rows x 64 cols, K=256 in 4 phases of BK=64,
// double-buffered LDS, A-frags in registers, one barrier per phase.
__global__ __launch_bounds__(512, 4) void neg_kernel(const float* __restrict__ vfeat,
                                                     const float* __restrict__ iou2d,
                                                     const unsigned short* __restrict__ posFrag,
                                                     float* __restrict__ part) {
    __shared__ unsigned short sB[2][2][4][64][8];   // [buf][s][ntile][slot][j]  16 KB
    __shared__ int   sIJ[64];
    __shared__ int   sMask[64];
    __shared__ float sNP[8][64];
    __shared__ float sInv[64];
    __shared__ float sNeg[RR];

    int tid = threadIdx.x;
    int bid = blockIdx.x;
    int b   = bid / BPB;
    int p0  = (bid - b * BPB) * 64;

    if (tid < RR) sNeg[tid] = 0.0f;
    if (tid < 64) {
        int p = p0 + tid;
        int i = (int)((257.0f - sqrtf(66049.0f - 8.0f * (float)p)) * 0.5f);
        if (i < 0) i = 0;
        while ((i + 1) * (257 - (i + 1)) / 2 <= p) ++i;
        while (i * (257 - i) / 2 > p) --i;
        int j = p - i * (257 - i) / 2 + i;
        int ij = i * NN + j;
        sIJ[tid] = ij;
        int mask = 0;
#pragma unroll
        for (int t = 0; t < 4; ++t) {
            float iv = iou2d[((size_t)(4 * b + t)) * NN2 + ij];
            mask |= (iv > NEGIOU) ? (1 << t) : 0;
        }
        sMask[tid] = mask;
    }

    int lane = tid & 63;
    int col  = tid & 63;
    int wv   = tid >> 6;                    // 0..7 (also the staging c-group tq)
    int rowgroup = wv >> 1;                 // 0..3 -> rows rowgroup*32
    int colgroup = wv & 1;                  // 0..1 -> cols colgroup*32

    // A fragments: 2 m-tiles x 8 k-steps, from global (L2/L3-hot, coalesced)
    bf16x8 afrag[2][8];
    const bf16x8* pf = (const bf16x8*)posFrag;
#pragma unroll
    for (int mt = 0; mt < 2; ++mt)
#pragma unroll
        for (int s = 0; s < 8; ++s)
            afrag[mt][s] = pf[(s * 8 + rowgroup * 2 + mt) * 64 + lane];

    __syncthreads();                        // sIJ/sMask ready

    const float* vcol = vfeat + (size_t)b * CDIM * NN2 + sIJ[col];

    f32x4 acc[2][2];
#pragma unroll
    for (int mt = 0; mt < 2; ++mt)
#pragma unroll
        for (int nt = 0; nt < 2; ++nt)
#pragma unroll
            for (int e = 0; e < 4; ++e) acc[mt][nt][e] = 0.0f;

    float nrm = 0.0f;
    float r[8];
#pragma unroll
    for (int j = 0; j < 8; ++j) r[j] = vcol[(size_t)(wv * 8 + j) * NN2];

    int s_loc = wv >> 2;
    int slot  = (col & 15) | ((wv & 3) << 4);
    int nt_w  = col >> 4;

    for (int ph = 0; ph < 4; ++ph) {
        // pack current phase's 8 fp32 -> bf16x8, write to LDS, accumulate norm
        union { bf16x8 v; unsigned u[4]; } pkd;
#pragma unroll
        for (int j = 0; j < 4; ++j)
            pkd.u[j] = (unsigned)f2bf(r[2 * j]) | ((unsigned)f2bf(r[2 * j + 1]) << 16);
#pragma unroll
        for (int j = 0; j < 8; ++j) nrm = fmaf(r[j], r[j], nrm);
        *(bf16x8*)&sB[ph & 1][s_loc][nt_w][slot][0] = pkd.v;
        __syncthreads();
        if (ph < 3) {
#pragma unroll
            for (int j = 0; j < 8; ++j)
                r[j] = vcol[(size_t)((ph + 1) * 64 + wv * 8 + j) * NN2];
        }
#pragma unroll
        for (int s = 0; s < 2; ++s)
#pragma unroll
            for (int ntl = 0; ntl < 2; ++ntl) {
                bf16x8 bfrag = *(const bf16x8*)&sB[ph & 1][s][colgroup * 2 + ntl][lane][0];
#pragma unroll
                for (int mt = 0; mt < 2; ++mt)
                    acc[mt][ntl] = __builtin_amdgcn_mfma_f32_16x16x32_bf16(
                        afrag[mt][ph * 2 + s], bfrag, acc[mt][ntl], 0, 0, 0);
            }
    }

    sNP[wv][col] = nrm;
    __syncthreads();
    if (tid < 64) {
        float s = 0.0f;
        for (int t = 0; t < 8; ++t) s += sNP[t][tid];
        sInv[tid] = 10.0f / fmaxf(sqrtf(s), 1e-12f);   // 1/(T*norm), T=0.1
    }
    __syncthreads();

    // epilogue: exp + mask + per-row reduce (C layout: col=lane&15, row=(lane>>4)*4+reg)
#pragma unroll
    for (int mt = 0; mt < 2; ++mt)
#pragma unroll
        for (int ntl = 0; ntl < 2; ++ntl)
#pragma unroll
            for (int reg = 0; reg < 4; ++reg) {
                int row = rowgroup * 32 + mt * 16 + ((lane >> 4) << 2) + reg;
                int cl  = colgroup * 32 + ntl * 16 + (lane & 15);
                float e = __expf(acc[mt][ntl][reg] * sInv[cl]);
                int excl = ((row >> 4) == b) & ((sMask[cl] >> ((row >> 2) & 3)) & 1);
                e = excl ? 0.0f : e;
#pragma unroll
                for (int off = 1; off < 16; off <<= 1) e += __shfl_xor(e, off, 64);
                if ((lane & 15) == 0) atomicAdd(&sNeg[row], e);
            }
    __syncthreads();
    if (tid < RR) part[(size_t)tid * NBLK + bid] = sNeg[tid];
}

// ---------------- Kernel 4: reduce per-block partials -> neg_sum[128] ------------
__global__ __launch_bounds__(256) void reduce_kernel(const float* __restrict__ part,
                                                     float* __restrict__ neg) {
    int r = blockIdx.x, tid = threadIdx.x;
    const float* row = part + (size_t)r * NBLK;
    float s = 0.0f;
    for (int t = tid; t < NBLK; t += 256) s += row[t];
#pragma unroll
    for (int o = 32; o > 0; o >>= 1) s += __shfl_xor(s, o, 64);
    __shared__ float sw[4];
    if ((tid & 63) == 0) sw[tid >> 6] = s;
    __syncthreads();
    if (tid == 0) neg[r] = sw[0] + sw[1] + sw[2] + sw[3];
}

// ---------------- Kernel 5: 512 pair dots + log-sum-exp + mean -------------------
__global__ __launch_bounds__(256) void loss_kernel(const float* __restrict__ pos,
                                                   const float* __restrict__ neg,
                                                   float* __restrict__ out) {
    int tid = threadIdx.x;
    float local = 0.0f;
    for (int e = tid; e < 512; e += 256) {
        int s  = e >> 4;
        int aa = (e >> 2) & 3;
        int bb = e & 3;
        int rr = s * 4 + aa;
        int pp = s * 4 + bb;
        const float4* pr = (const float4*)(pos + rr * CDIM);
        const float4* pq = (const float4*)(pos + pp * CDIM);
        float dot = 0.0f;
        for (int c = 0; c < CDIM / 4; ++c) {
            float4 a = pr[c], bv = pq[c];
            dot += a.x * bv.x + a.y * bv.y + a.z * bv.z + a.w * bv.w;
        }
        float x = dot / TEMP;                  // MARGIN = 0
        local += logf(__expf(x) + neg[rr]) - x;
    }
#pragma unroll
    for (int o = 32; o > 0; o >>= 1) local += __shfl_xor(local, o, 64);
    __shared__ float sred[4];
    if ((tid & 63) == 0) sred[tid >> 6] = local;
    __syncthreads();
    if (tid == 0) out[0] = (sred[0] + sred[1] + sred[2] + sred[3]) / 512.0f;
}

extern "C" void kernel_launch(void* const* d_in, const int* in_sizes, int n_in,
                              void* d_out, int out_size, void* d_ws, size_t ws_size,
                              hipStream_t stream) {
    (void)in_sizes; (void)n_in; (void)out_size; (void)ws_size;
    const float* vfeat  = (const float*)d_in[0];
    const float* iou2d  = (const float*)d_in[4];
    const float* iou2ds = (const float*)d_in[5];

    float* ws = (float*)d_ws;
    float*          pos     = ws;                                   // 32768 f
    unsigned short* posFrag = (unsigned short*)(ws + 32768);        // 32768 us = 16384 f
    float*          pv      = ws + 32768 + 16384;                   // 512 f
    int*            pk      = (int*)(pv + 512);                     // 512 i
    float*          part    = pv + 1024;                            // 128*1032 f
    float*          neg     = part + RR * NBLK;                     // 128 f

    topk_part_kernel<<<dim3(MM, 4), 256, 0, stream>>>(iou2ds, pv, pk);
    posfeat_kernel  <<<RR, 64, 0, stream>>>(vfeat, pv, pk, pos, posFrag);
    neg_kernel      <<<NBLK, 512, 0, stream>>>(vfeat, iou2d, posFrag, part);
    reduce_kernel   <<<RR, 256, 0, stream>>>(part, neg);
    loss_kernel     <<<1, 256, 0, stream>>>(pos, neg, (float*)d_out);
}